// Round 2
// 1358.277 us; speedup vs baseline: 1.5428x; 1.5428x over previous
//
#include <hip/hip_runtime.h>
#include <math.h>

#define D_MODEL 1024
#define D_STATE 128
#define NHEADS 32
#define HEADDIM 64
#define D_INNER 2048
#define D_IN_PROJ 4384
#define CONV_DIM 2304
#define LSEQ 1024
#define NCHUNK 16
#define VOCAB 50288
#define EPSF 1e-5f

#define NPAD_INPROJ 4480   /* 4384 -> 35*128 */
#define NPAD_VOCAB  50304  /* 50288 -> 393*128 */

#define CP 132             /* padded LDS row stride (floats): conflict-free float4 row reads */

typedef __bf16 bf16x8 __attribute__((ext_vector_type(8)));
typedef float  f32x4  __attribute__((ext_vector_type(4)));
typedef unsigned int u32;

__device__ __forceinline__ float silu_f(float v){ return v / (1.f + expf(-v)); }

__device__ __forceinline__ unsigned short f2bf(float f){
  unsigned int u = __float_as_uint(f);
  unsigned int r = (u + 0x7FFFu + ((u >> 16) & 1u)) >> 16;
  return (unsigned short)r;
}

__device__ __forceinline__ void gld_lds16(const void* g, void* l){
  __builtin_amdgcn_global_load_lds((const __attribute__((address_space(1))) u32*)g,
                                   (__attribute__((address_space(3))) u32*)l, 16, 0, 0);
}

// ---------------- fp32 -> bf16 cast with trailing zero-pad ----------------
__global__ __launch_bounds__(256) void castpad_k(const float* __restrict__ in,
                                                 unsigned short* __restrict__ out,
                                                 long n_in, long n_out){
  long i = ((long)blockIdx.x*256 + threadIdx.x)*8;
  if(i >= n_out) return;
  unsigned short v[8];
  if(i + 8 <= n_in){
    #pragma unroll
    for(int j=0;j<8;j++) v[j] = f2bf(in[i+j]);
  } else {
    #pragma unroll
    for(int j=0;j<8;j++){ long k=i+j; v[j] = (k < n_in) ? f2bf(in[k]) : (unsigned short)0; }
  }
  *(uint4*)&out[i] = *(const uint4*)v;
}

// ---------------- embedding gather ----------------
__global__ __launch_bounds__(256) void embed_k(const int* __restrict__ ids,
                                               const float* __restrict__ emb,
                                               float* __restrict__ x){
  int l = blockIdx.x;
  int d = blockIdx.y*256 + threadIdx.x;
  x[(size_t)l*D_MODEL + d] = emb[(size_t)ids[l]*D_MODEL + d];
}

// ---------------- rmsnorm (no gate), emits bf16 directly ----------------
__global__ __launch_bounds__(256) void rmsnorm_k(const float* __restrict__ x,
                                                 const float* __restrict__ w,
                                                 unsigned short* __restrict__ out, int D){
  int l = blockIdx.x;
  __shared__ float red[256];
  float s = 0.f;
  for(int i=threadIdx.x;i<D;i+=256){ float v = x[(size_t)l*D+i]; s += v*v; }
  red[threadIdx.x]=s; __syncthreads();
  for(int st=128;st>0;st>>=1){ if(threadIdx.x<st) red[threadIdx.x]+=red[threadIdx.x+st]; __syncthreads(); }
  float scale = rsqrtf(red[0]/(float)D + EPSF);
  for(int i=threadIdx.x;i<D;i+=256) out[(size_t)l*D+i] = f2bf(x[(size_t)l*D+i]*scale*w[i]);
}

// ---------------- bf16 MFMA GEMM: C[M,Nc] = A[M,K] @ B[Nb,K]^T (+res) ----------------
// m97 structure upgraded: XCD-aware block swizzle (T1) + double-buffered LDS with
// prefetch-before-compute and ONE barrier per K-step (minimum 2-phase, T3 recipe).
// Requires gridDim.x*gridDim.y % 8 == 0 (all our grids: 280 / 64 / 3144).
__global__ __launch_bounds__(256) void gemm_bt_mfma(
  const unsigned short* __restrict__ A, const unsigned short* __restrict__ B,
  const float* __restrict__ res, float* __restrict__ C,
  int M, int Nc, int K)
{
  __shared__ unsigned short sA[2][128*32];
  __shared__ unsigned short sB[2][128*32];
  const int tid  = threadIdx.x;
  const int wave = tid >> 6, lane = tid & 63;

  // XCD swizzle: each XCD gets a contiguous band of work, M-tile fastest inside,
  // so the 8 blocks sharing a B-panel co-reside on one XCD's L2.
  const int nwg  = gridDim.x*gridDim.y;
  const int flat = blockIdx.x + gridDim.x*blockIdx.y;
  const int per  = nwg >> 3;
  const int w    = (flat & 7)*per + (flat >> 3);
  const int m0 = (w % gridDim.x)*128;
  const int n0 = (w / gridDim.x)*128;

  const int wm = wave >> 1, wn = wave & 1;
  const int llo = lane & 15, lhi = lane >> 4;

  // wave-uniform LDS bases + per-lane global rows/cols for the two 512-elem stages
  const int eb0 = wave*1024;
  const int e0  = eb0 + lane*8;
  const int r0  = e0 >> 5, c0 = e0 & 31;
  const int eb1 = eb0 + 512;
  const int e1  = eb1 + lane*8;
  const int r1  = e1 >> 5, c1 = e1 & 31;

  f32x4 acc[4][4] = {};

  const int nt = K >> 5;
  // prologue: stage tile 0 into buf 0
  gld_lds16(A + (size_t)(m0+r0)*K + c0, &sA[0][eb0]);
  gld_lds16(A + (size_t)(m0+r1)*K + c1, &sA[0][eb1]);
  gld_lds16(B + (size_t)(n0+r0)*K + c0, &sB[0][eb0]);
  gld_lds16(B + (size_t)(n0+r1)*K + c1, &sB[0][eb1]);
  __syncthreads();   // drains vmcnt(0): tile 0 resident

  int cur = 0;
  for(int t=0;t<nt;t++){
    if(t+1 < nt){
      const int k0 = (t+1) << 5;
      gld_lds16(A + (size_t)(m0+r0)*K + k0 + c0, &sA[cur^1][eb0]);
      gld_lds16(A + (size_t)(m0+r1)*K + k0 + c1, &sA[cur^1][eb1]);
      gld_lds16(B + (size_t)(n0+r0)*K + k0 + c0, &sB[cur^1][eb0]);
      gld_lds16(B + (size_t)(n0+r1)*K + k0 + c1, &sB[cur^1][eb1]);
    }
    bf16x8 af[4], bfv[4];
    #pragma unroll
    for(int q=0;q<4;q++){
      af[q]  = *(const bf16x8*)&sA[cur][(wm*64 + q*16 + llo)*32 + lhi*8];
      bfv[q] = *(const bf16x8*)&sB[cur][(wn*64 + q*16 + llo)*32 + lhi*8];
    }
    #pragma unroll
    for(int i=0;i<4;i++)
      #pragma unroll
      for(int j=0;j<4;j++)
        acc[i][j] = __builtin_amdgcn_mfma_f32_16x16x32_bf16(af[i], bfv[j], acc[i][j], 0, 0, 0);
    __syncthreads();  // drains the prefetch (vmcnt 0) + protects buf reuse
    cur ^= 1;
  }

  // C/D layout: col = lane&15, row = (lane>>4)*4 + reg  [m89-verified]
  #pragma unroll
  for(int i=0;i<4;i++){
    #pragma unroll
    for(int j=0;j<4;j++){
      const int n = n0 + wn*64 + j*16 + llo;
      if(n < Nc){
        #pragma unroll
        for(int r=0;r<4;r++){
          const int m = m0 + wm*64 + i*16 + lhi*4 + r;
          float v = acc[i][j][r];
          if(res) v += res[(size_t)m*Nc + n];
          C[(size_t)m*Nc + n] = v;
        }
      }
    }
  }
}

// ---------------- dt softplus + dA ----------------
__global__ __launch_bounds__(256) void dt_k(const float* __restrict__ zxbcdt,
                                            const float* __restrict__ dt_bias,
                                            const float* __restrict__ A_log,
                                            float* __restrict__ dt, float* __restrict__ dA){
  int idx = blockIdx.x*256 + threadIdx.x; // LSEQ*32
  int l = idx >> 5, h = idx & 31;
  float v = zxbcdt[(size_t)l*D_IN_PROJ + D_INNER + CONV_DIM + h] + dt_bias[h];
  float sp = v > 20.f ? v : log1pf(expf(v));
  dt[idx] = sp;
  dA[idx] = -expf(A_log[h]) * sp;
}

// ---------------- depthwise causal conv1d (w=4) + silu ----------------
__global__ __launch_bounds__(256) void conv_silu_k(const float* __restrict__ zxbcdt,
                                                   const float* __restrict__ cw,
                                                   const float* __restrict__ cb,
                                                   float* __restrict__ xBCs){
  int c = blockIdx.x*256 + threadIdx.x;
  int l = blockIdx.y;
  if(c >= CONV_DIM) return;
  float acc = cb[c];
  #pragma unroll
  for(int j=0;j<4;j++){
    int t = l - 3 + j;
    if(t >= 0) acc += zxbcdt[(size_t)t*D_IN_PROJ + D_INNER + c] * cw[c*4+j];
  }
  xBCs[(size_t)l*CONV_DIM + c] = silu_f(acc);
}

// ---------------- per-(chunk,head): Y_diag + chunk states ----------------
// LDS rows padded to CP=132 floats: row-strided float4 reads (different row,
// same column per lane) become conflict-free: bank = (132*s+4n) mod 32 covers
// all banks across an 8-lane group.
__global__ __launch_bounds__(256) void chunk_k(
  const float* __restrict__ xBCs, const float* __restrict__ dt, const float* __restrict__ dA,
  float* __restrict__ ydiag, float* __restrict__ states,
  float* __restrict__ acs_out, float* __restrict__ easum_out)
{
  const int c = blockIdx.x, h = blockIdx.y;
  __shared__ float sB[64][CP];
  __shared__ float sC[64][CP];
  __shared__ float sX[64][64];
  __shared__ float sM[64][64];
  __shared__ float sDec[64];
  __shared__ float acs[64];
  const int tid = threadIdx.x;
  // float4-vectorized staging of B/C (64x128 each)
  for(int i=tid;i<2048;i+=256){
    int t=i>>5, n=(i&31)<<2; int l=c*64+t;
    float4 bv = *(const float4*)&xBCs[(size_t)l*CONV_DIM + D_INNER + n];
    float4 cv = *(const float4*)&xBCs[(size_t)l*CONV_DIM + D_INNER + D_STATE + n];
    *(float4*)&sB[t][n] = bv;
    *(float4*)&sC[t][n] = cv;
  }
  for(int i=tid;i<1024;i+=256){
    int t=i>>4, p=(i&15)<<2; int l=c*64+t;
    float4 xv = *(const float4*)&xBCs[(size_t)l*CONV_DIM + h*64 + p];
    float dtl = dt[l*32+h];
    xv.x*=dtl; xv.y*=dtl; xv.z*=dtl; xv.w*=dtl;
    *(float4*)&sX[t][p] = xv;
  }
  if(tid==0){ float s=0.f; for(int t=0;t<64;t++){ s+=dA[(c*64+t)*32+h]; acs[t]=s; } }
  __syncthreads();
  if(tid<64) sDec[tid]=expf(acs[63]-acs[tid]);
  for(int i=tid;i<4096;i+=256){
    int t=i>>6, s=i&63;
    float v=0.f;
    if(s<=t){
      const float4* c4=(const float4*)sC[t];
      const float4* b4=(const float4*)sB[s];
      float4 g={0,0,0,0};
      #pragma unroll 8
      for(int n=0;n<32;n++){ float4 cv=c4[n], bv=b4[n];
        g.x+=cv.x*bv.x; g.y+=cv.y*bv.y; g.z+=cv.z*bv.z; g.w+=cv.w*bv.w; }
      v=(g.x+g.y+g.z+g.w)*expf(acs[t]-acs[s]);
    }
    sM[t][s]=v;
  }
  __syncthreads();
  for(int i=tid;i<1024;i+=256){
    int t=i>>4, p4=(i&15)*4;
    float4 acc={0,0,0,0};
    for(int s=0;s<=t;s++){
      float m=sM[t][s];
      float4 xv=*(const float4*)&sX[s][p4];
      acc.x+=m*xv.x; acc.y+=m*xv.y; acc.z+=m*xv.z; acc.w+=m*xv.w;
    }
    int l=c*64+t;
    *(float4*)&ydiag[(size_t)l*D_INNER + h*64 + p4]=acc;
  }
  for(int i=tid;i<2048;i+=256){
    int p=i>>5, n4=(i&31)*4;
    float4 acc={0,0,0,0};
    for(int t=0;t<64;t++){
      float w=sX[t][p]*sDec[t];
      float4 bv=*(const float4*)&sB[t][n4];
      acc.x+=w*bv.x; acc.y+=w*bv.y; acc.z+=w*bv.z; acc.w+=w*bv.w;
    }
    *(float4*)&states[((size_t)(c*32+h)*64 + p)*128 + n4]=acc;
  }
  for(int t=tid;t<64;t+=256) acs_out[(c*32+h)*64+t]=acs[t];
  if(tid==0) easum_out[c*32+h]=expf(acs[63]);   // pre-exponentiated for scan_k
}

// ---------------- cross-chunk scan ----------------
__global__ __launch_bounds__(256) void scan_k(const float* __restrict__ states,
                                              const float* __restrict__ easum,
                                              float* __restrict__ istates){
  int idx = blockIdx.x*256 + threadIdx.x; // 32*64*128 = 262144
  int h = idx >> 13;
  float S = 0.f;
  for(int c=0;c<NCHUNK;c++){
    size_t off = (size_t)c*262144 + idx;
    istates[off] = S;
    S = S*easum[c*32+h] + states[off];
  }
}

// ---------------- Y_off + D skip ----------------
__global__ __launch_bounds__(256) void yoff_k(
  const float* __restrict__ xBCs, const float* __restrict__ istates,
  const float* __restrict__ acs_in, const float* __restrict__ Ds,
  float* __restrict__ y)
{
  const int c=blockIdx.x, h=blockIdx.y;
  __shared__ float sS[64][CP];
  __shared__ float sC[64][CP];
  __shared__ float sE[64];
  const int tid=threadIdx.x;
  for(int i=tid;i<2048;i+=256){
    int t=i>>5, n=(i&31)<<2;
    float4 sv = *(const float4*)&istates[(size_t)c*262144 + h*8192 + (size_t)t*128 + n];
    float4 cv = *(const float4*)&xBCs[(size_t)(c*64+t)*CONV_DIM + D_INNER + D_STATE + n];
    *(float4*)&sS[t][n] = sv;
    *(float4*)&sC[t][n] = cv;
  }
  if(tid<64) sE[tid]=expf(acs_in[(c*32+h)*64+tid]);
  __syncthreads();
  const float Dh=Ds[h];
  for(int i=tid;i<4096;i+=256){
    int t=i>>6, p=i&63;
    const float4* c4=(const float4*)sC[t];
    const float4* s4=(const float4*)sS[p];
    float4 g={0,0,0,0};
    #pragma unroll 8
    for(int n=0;n<32;n++){ float4 cv=c4[n], sv=s4[n];
      g.x+=cv.x*sv.x; g.y+=cv.y*sv.y; g.z+=cv.z*sv.z; g.w+=cv.w*sv.w; }
    int l=c*64+t;
    size_t yi=(size_t)l*D_INNER + h*64 + p;
    float xorig=xBCs[(size_t)l*CONV_DIM + h*64 + p];
    y[yi] = y[yi] + sE[t]*(g.x+g.y+g.z+g.w) + xorig*Dh;
  }
}

// ---------------- gated rmsnorm, emits bf16 directly ----------------
__global__ __launch_bounds__(256) void gnorm_k(const float* __restrict__ y,
                                               const float* __restrict__ zxbcdt,
                                               const float* __restrict__ w,
                                               unsigned short* __restrict__ out){
  int l=blockIdx.x;
  __shared__ float red[256];
  float s=0.f;
  for(int i=threadIdx.x;i<D_INNER;i+=256){
    float z=zxbcdt[(size_t)l*D_IN_PROJ + i];
    float v=y[(size_t)l*D_INNER+i]*silu_f(z);
    s+=v*v;
  }
  red[threadIdx.x]=s; __syncthreads();
  for(int st=128;st>0;st>>=1){ if(threadIdx.x<st) red[threadIdx.x]+=red[threadIdx.x+st]; __syncthreads(); }
  float scale=rsqrtf(red[0]/(float)D_INNER + EPSF);
  for(int i=threadIdx.x;i<D_INNER;i+=256){
    float z=zxbcdt[(size_t)l*D_IN_PROJ + i];
    float v=y[(size_t)l*D_INNER+i]*silu_f(z);
    out[(size_t)l*D_INNER+i]=f2bf(v*scale*w[i]);
  }
}

extern "C" void kernel_launch(void* const* d_in, const int* in_sizes, int n_in,
                              void* d_out, int out_size, void* d_ws, size_t ws_size,
                              hipStream_t stream)
{
  const int*   ids      = (const int*)  d_in[0];
  const float* emb      = (const float*)d_in[1];
  const float* norm_ws  = (const float*)d_in[2];
  const float* in_ws    = (const float*)d_in[3];
  const float* conv_ws  = (const float*)d_in[4];
  const float* conv_bs  = (const float*)d_in[5];
  const float* dt_bias  = (const float*)d_in[6];
  const float* A_logs   = (const float*)d_in[7];
  const float* Ds       = (const float*)d_in[8];
  const float* gnorm_ws = (const float*)d_in[9];
  const float* out_ws   = (const float*)d_in[10];
  const float* norm_f_w = (const float*)d_in[11];
  float* out = (float*)d_out;

  float* ws      = (float*)d_ws;
  float* x       = ws;                       // 1048576
  float* zxbcdt  = x + 1048576;              // 4489216
  float* xBCs    = zxbcdt + 4489216;         // 2359296
  float* dtb     = xBCs + 2359296;           // 32768
  float* dAb     = dtb + 32768;              // 32768
  float* acs     = dAb + 32768;              // 32768
  float* easum   = acs + 32768;              // 512
  float* yb      = easum + 512;              // 2097152
  float* states  = yb + 2097152;             // 4194304
  float* istates = states + 4194304;         // 4194304
  // bf16 region (unsigned short), 16B-aligned (float offset total is mult of 4)
  unsigned short* bfbase   = (unsigned short*)(istates + 4194304);
  unsigned short* u_bf     = bfbase;                 // 1048576
  unsigned short* yg_bf    = u_bf  + 1048576;        // 2097152
  unsigned short* in_wb    = yg_bf + 2097152;        // 4480*1024 = 4587520
  unsigned short* out_wb   = in_wb + 4587520;        // 2097152
  unsigned short* emb_bf   = out_wb + 2097152;       // 50304*1024 = 51511296

  embed_k<<<dim3(1024,4),256,0,stream>>>(ids, emb, x);
  castpad_k<<<25152,256,0,stream>>>(emb, emb_bf, (long)VOCAB*D_MODEL, (long)NPAD_VOCAB*D_MODEL);

  for(int i=0;i<4;i++){
    rmsnorm_k<<<1024,256,0,stream>>>(x, norm_ws + i*1024, u_bf, D_MODEL);
    castpad_k<<<2240,256,0,stream>>>(in_ws + (size_t)i*4489216, in_wb,
                                     4489216L, (long)NPAD_INPROJ*D_MODEL);
    gemm_bt_mfma<<<dim3(8,35),256,0,stream>>>(u_bf, in_wb, nullptr, zxbcdt,
                                              1024, D_IN_PROJ, D_MODEL);
    dt_k<<<128,256,0,stream>>>(zxbcdt, dt_bias + i*32, A_logs + i*32, dtb, dAb);
    conv_silu_k<<<dim3(9,1024),256,0,stream>>>(zxbcdt, conv_ws + i*(CONV_DIM*4),
                                               conv_bs + i*CONV_DIM, xBCs);
    chunk_k<<<dim3(16,32),256,0,stream>>>(xBCs, dtb, dAb, yb, states, acs, easum);
    scan_k<<<1024,256,0,stream>>>(states, easum, istates);
    yoff_k<<<dim3(16,32),256,0,stream>>>(xBCs, istates, acs, Ds + i*32, yb);
    gnorm_k<<<1024,256,0,stream>>>(yb, zxbcdt, gnorm_ws + i*D_INNER, yg_bf);
    castpad_k<<<1024,256,0,stream>>>(out_ws + (size_t)i*2097152, out_wb, 2097152L, 2097152L);
    gemm_bt_mfma<<<dim3(8,8),256,0,stream>>>(yg_bf, out_wb, x, x,
                                             1024, D_MODEL, D_INNER);
  }

  rmsnorm_k<<<1024,256,0,stream>>>(x, norm_f_w, u_bf, D_MODEL);
  gemm_bt_mfma<<<dim3(8,393),256,0,stream>>>(u_bf, emb_bf, nullptr, out,
                                             1024, VOCAB, D_MODEL);
}

// Round 3
// 1277.336 us; speedup vs baseline: 1.6405x; 1.0634x over previous
//
#include <hip/hip_runtime.h>
#include <math.h>

#define D_MODEL 1024
#define D_STATE 128
#define NHEADS 32
#define HEADDIM 64
#define D_INNER 2048
#define D_IN_PROJ 4384
#define CONV_DIM 2304
#define LSEQ 1024
#define NCHUNK 16
#define VOCAB 50288
#define EPSF 1e-5f

#define NPAD_INPROJ 4480   /* 4384 -> 35*128 */
#define NPAD_VOCAB  50304  /* 50288 -> 393*128 */

#define CP 132             /* padded LDS row stride (floats) */

typedef __bf16 bf16x8 __attribute__((ext_vector_type(8)));
typedef float  f32x4  __attribute__((ext_vector_type(4)));
typedef unsigned int u32;

__device__ __forceinline__ float silu_f(float v){ return v / (1.f + expf(-v)); }

__device__ __forceinline__ unsigned short f2bf(float f){
  unsigned int u = __float_as_uint(f);
  unsigned int r = (u + 0x7FFFu + ((u >> 16) & 1u)) >> 16;
  return (unsigned short)r;
}

__device__ __forceinline__ void gld_lds16(const void* g, void* l){
  __builtin_amdgcn_global_load_lds((const __attribute__((address_space(1))) u32*)g,
                                   (__attribute__((address_space(3))) u32*)l, 16, 0, 0);
}

// ---------------- fp32 -> bf16 cast with trailing zero-pad ----------------
__global__ __launch_bounds__(256) void castpad_k(const float* __restrict__ in,
                                                 unsigned short* __restrict__ out,
                                                 long n_in, long n_out){
  long i = ((long)blockIdx.x*256 + threadIdx.x)*8;
  if(i >= n_out) return;
  unsigned short v[8];
  if(i + 8 <= n_in){
    #pragma unroll
    for(int j=0;j<8;j++) v[j] = f2bf(in[i+j]);
  } else {
    #pragma unroll
    for(int j=0;j<8;j++){ long k=i+j; v[j] = (k < n_in) ? f2bf(in[k]) : (unsigned short)0; }
  }
  *(uint4*)&out[i] = *(const uint4*)v;
}

// ---------------- embedding gather ----------------
__global__ __launch_bounds__(256) void embed_k(const int* __restrict__ ids,
                                               const float* __restrict__ emb,
                                               float* __restrict__ x){
  int l = blockIdx.x;
  int d = blockIdx.y*256 + threadIdx.x;
  x[(size_t)l*D_MODEL + d] = emb[(size_t)ids[l]*D_MODEL + d];
}

// ---------------- rmsnorm (no gate), emits bf16 directly ----------------
__global__ __launch_bounds__(256) void rmsnorm_k(const float* __restrict__ x,
                                                 const float* __restrict__ w,
                                                 unsigned short* __restrict__ out, int D){
  int l = blockIdx.x;
  __shared__ float red[256];
  float s = 0.f;
  for(int i=threadIdx.x;i<D;i+=256){ float v = x[(size_t)l*D+i]; s += v*v; }
  red[threadIdx.x]=s; __syncthreads();
  for(int st=128;st>0;st>>=1){ if(threadIdx.x<st) red[threadIdx.x]+=red[threadIdx.x+st]; __syncthreads(); }
  float scale = rsqrtf(red[0]/(float)D + EPSF);
  for(int i=threadIdx.x;i<D;i+=256) out[(size_t)l*D+i] = f2bf(x[(size_t)l*D+i]*scale*w[i]);
}

// ---------------- bf16 MFMA GEMM: C[M,Nc] = A[M,K] @ B[Nb,K]^T (+res) ----------------
// 128x128 tile, BK=64 (32 MFMA per barrier), XCD swizzle (T1), double-buffered LDS
// with prefetch-before-compute (minimum 2-phase, T3 recipe), both-sides XOR LDS
// swizzle (T2 / rule 21: pre-swizzled global source for global_load_lds, same XOR
// on ds_read), transposed MFMA accumulate -> float4 C stores.
// Requires M%128==0, K%64==0, Nb%128==0, Nc%4==0, grid %8==0.
__global__ __launch_bounds__(256) void gemm_bt_mfma(
  const unsigned short* __restrict__ A, const unsigned short* __restrict__ B,
  const float* __restrict__ res, float* __restrict__ C,
  int M, int Nc, int K)
{
  __shared__ unsigned short sA[2][128*64];
  __shared__ unsigned short sB[2][128*64];
  const int tid  = threadIdx.x;
  const int wave = tid >> 6, lane = tid & 63;

  // XCD swizzle: contiguous band per XCD, M-tile fastest inside.
  const int nwg  = gridDim.x*gridDim.y;
  const int flat = blockIdx.x + gridDim.x*blockIdx.y;
  const int per  = nwg >> 3;
  const int w    = (flat & 7)*per + (flat >> 3);
  const int m0 = (w % gridDim.x)*128;
  const int n0 = (w / gridDim.x)*128;

  const int wm = wave >> 1, wn = wave & 1;
  const int llo = lane & 15, lhi = lane >> 4;

  // staging: 4 chunks/matrix; elem e = q*2048 + tid*8; row = q*32 + wave*8 + (lane>>3)
  // global col chunk pre-swizzled: ck = (lane&7) ^ (lane>>3)   (row&7 == lane>>3)
  const int scol = (((lane&7) ^ (lane>>3)) << 3);
  int srow[4];
  #pragma unroll
  for(int q=0;q<4;q++) srow[q] = q*32 + wave*8 + (lane>>3);
  const int sbase0 = wave*512;  // + q*2048, wave-uniform element base

  f32x4 acc[4][4] = {};
  const int nt = K >> 6;

  // prologue: stage tile 0 into buf 0
  #pragma unroll
  for(int q=0;q<4;q++){
    gld_lds16(A + (size_t)(m0+srow[q])*K + scol, &sA[0][q*2048 + sbase0]);
    gld_lds16(B + (size_t)(n0+srow[q])*K + scol, &sB[0][q*2048 + sbase0]);
  }
  __syncthreads();

  int cur = 0;
  for(int t=0;t<nt;t++){
    if(t+1 < nt){
      const int k0 = (t+1) << 6;
      #pragma unroll
      for(int q=0;q<4;q++){
        gld_lds16(A + (size_t)(m0+srow[q])*K + k0 + scol, &sA[cur^1][q*2048 + sbase0]);
        gld_lds16(B + (size_t)(n0+srow[q])*K + k0 + scol, &sB[cur^1][q*2048 + sbase0]);
      }
    }
    #pragma unroll
    for(int kk=0;kk<2;kk++){
      bf16x8 af[4], bfv[4];
      const int ck = (((lhi + kk*4) ^ (llo&7)) << 3);  // swizzled col chunk (rows&7 == llo&7)
      #pragma unroll
      for(int q=0;q<4;q++){
        af[q]  = *(const bf16x8*)&sA[cur][(wm*64 + q*16 + llo)*64 + ck];
        bfv[q] = *(const bf16x8*)&sB[cur][(wn*64 + q*16 + llo)*64 + ck];
      }
      #pragma unroll
      for(int i=0;i<4;i++)
        #pragma unroll
        for(int j=0;j<4;j++)
          acc[i][j] = __builtin_amdgcn_mfma_f32_16x16x32_bf16(bfv[j], af[i], acc[i][j], 0, 0, 0);
    }
    __syncthreads();
    cur ^= 1;
  }

  // transposed D: row'=(lane>>4)*4+reg -> n-index, col'=lane&15 -> m-index
  // lane stores float4 at C[m][nb], m = m0+wm*64+i*16+llo, nb = n0+wn*64+j*16+lhi*4
  #pragma unroll
  for(int i=0;i<4;i++){
    const int m = m0 + wm*64 + i*16 + llo;
    #pragma unroll
    for(int j=0;j<4;j++){
      const int nb = n0 + wn*64 + j*16 + lhi*4;
      if(nb < Nc){
        float4 v = *(float4*)&acc[i][j];
        if(res){
          float4 rv = *(const float4*)&res[(size_t)m*Nc + nb];
          v.x+=rv.x; v.y+=rv.y; v.z+=rv.z; v.w+=rv.w;
        }
        *(float4*)&C[(size_t)m*Nc + nb] = v;
      }
    }
  }
}

// ---------------- dt softplus + dA ----------------
__global__ __launch_bounds__(256) void dt_k(const float* __restrict__ zxbcdt,
                                            const float* __restrict__ dt_bias,
                                            const float* __restrict__ A_log,
                                            float* __restrict__ dt, float* __restrict__ dA){
  int idx = blockIdx.x*256 + threadIdx.x; // LSEQ*32
  int l = idx >> 5, h = idx & 31;
  float v = zxbcdt[(size_t)l*D_IN_PROJ + D_INNER + CONV_DIM + h] + dt_bias[h];
  float sp = v > 20.f ? v : log1pf(expf(v));
  dt[idx] = sp;
  dA[idx] = -expf(A_log[h]) * sp;
}

// ---------------- depthwise causal conv1d (w=4) + silu ----------------
__global__ __launch_bounds__(256) void conv_silu_k(const float* __restrict__ zxbcdt,
                                                   const float* __restrict__ cw,
                                                   const float* __restrict__ cb,
                                                   float* __restrict__ xBCs){
  int c = blockIdx.x*256 + threadIdx.x;
  int l = blockIdx.y;
  if(c >= CONV_DIM) return;
  float acc = cb[c];
  #pragma unroll
  for(int j=0;j<4;j++){
    int t = l - 3 + j;
    if(t >= 0) acc += zxbcdt[(size_t)t*D_IN_PROJ + D_INNER + c] * cw[c*4+j];
  }
  xBCs[(size_t)l*CONV_DIM + c] = silu_f(acc);
}

// ---------------- per-chunk: G = C @ B^T (head-independent, computed ONCE) ----
__global__ __launch_bounds__(256) void gcb_k(const float* __restrict__ xBCs,
                                             float* __restrict__ gbuf){
  const int c = blockIdx.x;
  __shared__ float sB[64][CP];
  __shared__ float sC[64][CP];
  const int tid = threadIdx.x;
  for(int i=tid;i<2048;i+=256){
    int t=i>>5, n=(i&31)<<2; int l=c*64+t;
    *(float4*)&sB[t][n] = *(const float4*)&xBCs[(size_t)l*CONV_DIM + D_INNER + n];
    *(float4*)&sC[t][n] = *(const float4*)&xBCs[(size_t)l*CONV_DIM + D_INNER + D_STATE + n];
  }
  __syncthreads();
  for(int i=tid;i<4096;i+=256){
    int t=i>>6, s=i&63;
    float v=0.f;
    if(s<=t){
      const float4* c4=(const float4*)sC[t];
      const float4* b4=(const float4*)sB[s];
      float4 g={0,0,0,0};
      #pragma unroll 8
      for(int n=0;n<32;n++){ float4 cv=c4[n], bv=b4[n];
        g.x+=cv.x*bv.x; g.y+=cv.y*bv.y; g.z+=cv.z*bv.z; g.w+=cv.w*bv.w; }
      v=g.x+g.y+g.z+g.w;
    }
    gbuf[(size_t)c*4096 + i]=v;
  }
}

// ---------------- per-(chunk,head): Y_diag + chunk states ----------------
// G loaded from gbuf (shared across heads); scaled in-LDS by exp(acs[t]-acs[s]).
// LDS 65.5 KB -> 2 blocks/CU. acs cumsum via wave-0 shfl scan (no serial loop).
__global__ __launch_bounds__(256) void chunk_k(
  const float* __restrict__ xBCs, const float* __restrict__ dt, const float* __restrict__ dA,
  const float* __restrict__ gbuf,
  float* __restrict__ ydiag, float* __restrict__ states,
  float* __restrict__ acs_out, float* __restrict__ easum_out)
{
  const int c = blockIdx.x, h = blockIdx.y;
  __shared__ float sB[64][CP];
  __shared__ float sM[64][64];
  __shared__ float sX[64][64];
  __shared__ float sDec[64];
  __shared__ float acs[64];
  const int tid = threadIdx.x;
  const int wave = tid>>6, lane = tid&63;

  for(int i=tid;i<2048;i+=256){
    int t=i>>5, n=(i&31)<<2; int l=c*64+t;
    *(float4*)&sB[t][n] = *(const float4*)&xBCs[(size_t)l*CONV_DIM + D_INNER + n];
  }
  for(int i=tid;i<1024;i+=256){
    int t=i>>4, p=(i&15)<<2; int l=c*64+t;
    float4 xv = *(const float4*)&xBCs[(size_t)l*CONV_DIM + h*64 + p];
    float dtl = dt[l*32+h];
    xv.x*=dtl; xv.y*=dtl; xv.z*=dtl; xv.w*=dtl;
    *(float4*)&sX[t][p] = xv;
  }
  for(int i=tid;i<4096;i+=256) ((float*)sM)[i] = gbuf[(size_t)c*4096 + i];
  if(wave==0){
    float a = dA[(size_t)(c*64+lane)*32 + h];
    #pragma unroll
    for(int off=1;off<64;off<<=1){
      float up = __shfl_up(a, off, 64);
      if(lane>=off) a += up;
    }
    acs[lane]=a;
    float tot = __shfl(a, 63, 64);
    sDec[lane]=expf(tot-a);
    if(lane==63) easum_out[c*32+h]=expf(a);
  }
  __syncthreads();
  for(int i=tid;i<4096;i+=256){
    int t=i>>6, s=i&63;
    sM[t][s] = (s<=t) ? sM[t][s]*expf(acs[t]-acs[s]) : 0.f;
  }
  __syncthreads();
  for(int i=tid;i<1024;i+=256){
    int t=i>>4, p4=(i&15)*4;
    float4 acc={0,0,0,0};
    for(int s=0;s<=t;s++){
      float m=sM[t][s];
      float4 xv=*(const float4*)&sX[s][p4];
      acc.x+=m*xv.x; acc.y+=m*xv.y; acc.z+=m*xv.z; acc.w+=m*xv.w;
    }
    int l=c*64+t;
    *(float4*)&ydiag[(size_t)l*D_INNER + h*64 + p4]=acc;
  }
  for(int i=tid;i<2048;i+=256){
    int p=i>>5, n4=(i&31)*4;
    float4 acc={0,0,0,0};
    for(int t=0;t<64;t++){
      float w=sX[t][p]*sDec[t];
      float4 bv=*(const float4*)&sB[t][n4];
      acc.x+=w*bv.x; acc.y+=w*bv.y; acc.z+=w*bv.z; acc.w+=w*bv.w;
    }
    *(float4*)&states[((size_t)(c*32+h)*64 + p)*128 + n4]=acc;
  }
  for(int t=tid;t<64;t+=256) acs_out[(c*32+h)*64+t]=acs[t];
}

// ---------------- cross-chunk scan ----------------
__global__ __launch_bounds__(256) void scan_k(const float* __restrict__ states,
                                              const float* __restrict__ easum,
                                              float* __restrict__ istates){
  int idx = blockIdx.x*256 + threadIdx.x; // 32*64*128 = 262144
  int h = idx >> 13;
  float S = 0.f;
  for(int c=0;c<NCHUNK;c++){
    size_t off = (size_t)c*262144 + idx;
    istates[off] = S;
    S = S*easum[c*32+h] + states[off];
  }
}

// ---------------- Y_off + D skip ----------------
__global__ __launch_bounds__(256) void yoff_k(
  const float* __restrict__ xBCs, const float* __restrict__ istates,
  const float* __restrict__ acs_in, const float* __restrict__ Ds,
  float* __restrict__ y)
{
  const int c=blockIdx.x, h=blockIdx.y;
  __shared__ float sS[64][CP];
  __shared__ float sC[64][CP];
  __shared__ float sE[64];
  const int tid=threadIdx.x;
  for(int i=tid;i<2048;i+=256){
    int t=i>>5, n=(i&31)<<2;
    float4 sv = *(const float4*)&istates[(size_t)c*262144 + h*8192 + (size_t)t*128 + n];
    float4 cv = *(const float4*)&xBCs[(size_t)(c*64+t)*CONV_DIM + D_INNER + D_STATE + n];
    *(float4*)&sS[t][n] = sv;
    *(float4*)&sC[t][n] = cv;
  }
  if(tid<64) sE[tid]=expf(acs_in[(c*32+h)*64+tid]);
  __syncthreads();
  const float Dh=Ds[h];
  for(int i=tid;i<4096;i+=256){
    int t=i>>6, p=i&63;
    const float4* c4=(const float4*)sC[t];
    const float4* s4=(const float4*)sS[p];
    float4 g={0,0,0,0};
    #pragma unroll 8
    for(int n=0;n<32;n++){ float4 cv=c4[n], sv=s4[n];
      g.x+=cv.x*sv.x; g.y+=cv.y*sv.y; g.z+=cv.z*sv.z; g.w+=cv.w*sv.w; }
    int l=c*64+t;
    size_t yi=(size_t)l*D_INNER + h*64 + p;
    float xorig=xBCs[(size_t)l*CONV_DIM + h*64 + p];
    y[yi] = y[yi] + sE[t]*(g.x+g.y+g.z+g.w) + xorig*Dh;
  }
}

// ---------------- gated rmsnorm, emits bf16 directly ----------------
__global__ __launch_bounds__(256) void gnorm_k(const float* __restrict__ y,
                                               const float* __restrict__ zxbcdt,
                                               const float* __restrict__ w,
                                               unsigned short* __restrict__ out){
  int l=blockIdx.x;
  __shared__ float red[256];
  float s=0.f;
  for(int i=threadIdx.x;i<D_INNER;i+=256){
    float z=zxbcdt[(size_t)l*D_IN_PROJ + i];
    float v=y[(size_t)l*D_INNER+i]*silu_f(z);
    s+=v*v;
  }
  red[threadIdx.x]=s; __syncthreads();
  for(int st=128;st>0;st>>=1){ if(threadIdx.x<st) red[threadIdx.x]+=red[threadIdx.x+st]; __syncthreads(); }
  float scale=rsqrtf(red[0]/(float)D_INNER + EPSF);
  for(int i=threadIdx.x;i<D_INNER;i+=256){
    float z=zxbcdt[(size_t)l*D_IN_PROJ + i];
    float v=y[(size_t)l*D_INNER+i]*silu_f(z);
    out[(size_t)l*D_INNER+i]=f2bf(v*scale*w[i]);
  }
}

extern "C" void kernel_launch(void* const* d_in, const int* in_sizes, int n_in,
                              void* d_out, int out_size, void* d_ws, size_t ws_size,
                              hipStream_t stream)
{
  const int*   ids      = (const int*)  d_in[0];
  const float* emb      = (const float*)d_in[1];
  const float* norm_ws  = (const float*)d_in[2];
  const float* in_ws    = (const float*)d_in[3];
  const float* conv_ws  = (const float*)d_in[4];
  const float* conv_bs  = (const float*)d_in[5];
  const float* dt_bias  = (const float*)d_in[6];
  const float* A_logs   = (const float*)d_in[7];
  const float* Ds       = (const float*)d_in[8];
  const float* gnorm_ws = (const float*)d_in[9];
  const float* out_ws   = (const float*)d_in[10];
  const float* norm_f_w = (const float*)d_in[11];
  float* out = (float*)d_out;

  float* ws      = (float*)d_ws;
  float* x       = ws;                       // 1048576
  float* zxbcdt  = x + 1048576;              // 4489216
  float* xBCs    = zxbcdt + 4489216;         // 2359296
  float* dtb     = xBCs + 2359296;           // 32768
  float* dAb     = dtb + 32768;              // 32768
  float* acs     = dAb + 32768;              // 32768
  float* easum   = acs + 32768;              // 512
  float* gbuf    = easum + 512;              // 65536 (16 chunks x 64x64)
  float* yb      = gbuf + 65536;             // 2097152
  float* states  = yb + 2097152;             // 4194304
  float* istates = states + 4194304;         // 4194304
  // bf16 region (unsigned short), 16B-aligned
  unsigned short* bfbase   = (unsigned short*)(istates + 4194304);
  unsigned short* u_bf     = bfbase;                 // 1048576
  unsigned short* yg_bf    = u_bf  + 1048576;        // 2097152
  unsigned short* in_wb    = yg_bf + 2097152;        // 4480*1024 = 4587520
  unsigned short* out_wb   = in_wb + 4587520;        // 2097152
  unsigned short* emb_bf   = out_wb + 2097152;       // 50304*1024 = 51511296

  embed_k<<<dim3(1024,4),256,0,stream>>>(ids, emb, x);
  castpad_k<<<25152,256,0,stream>>>(emb, emb_bf, (long)VOCAB*D_MODEL, (long)NPAD_VOCAB*D_MODEL);

  for(int i=0;i<4;i++){
    rmsnorm_k<<<1024,256,0,stream>>>(x, norm_ws + i*1024, u_bf, D_MODEL);
    castpad_k<<<2240,256,0,stream>>>(in_ws + (size_t)i*4489216, in_wb,
                                     4489216L, (long)NPAD_INPROJ*D_MODEL);
    gemm_bt_mfma<<<dim3(8,35),256,0,stream>>>(u_bf, in_wb, nullptr, zxbcdt,
                                              1024, D_IN_PROJ, D_MODEL);
    dt_k<<<128,256,0,stream>>>(zxbcdt, dt_bias + i*32, A_logs + i*32, dtb, dAb);
    conv_silu_k<<<dim3(9,1024),256,0,stream>>>(zxbcdt, conv_ws + i*(CONV_DIM*4),
                                               conv_bs + i*CONV_DIM, xBCs);
    gcb_k<<<16,256,0,stream>>>(xBCs, gbuf);
    chunk_k<<<dim3(16,32),256,0,stream>>>(xBCs, dtb, dAb, gbuf, yb, states, acs, easum);
    scan_k<<<1024,256,0,stream>>>(states, easum, istates);
    yoff_k<<<dim3(16,32),256,0,stream>>>(xBCs, istates, acs, Ds + i*32, yb);
    gnorm_k<<<1024,256,0,stream>>>(yb, zxbcdt, gnorm_ws + i*D_INNER, yg_bf);
    castpad_k<<<1024,256,0,stream>>>(out_ws + (size_t)i*2097152, out_wb, 2097152L, 2097152L);
    gemm_bt_mfma<<<dim3(8,8),256,0,stream>>>(yg_bf, out_wb, x, x,
                                             1024, D_MODEL, D_INNER);
  }

  rmsnorm_k<<<1024,256,0,stream>>>(x, norm_f_w, u_bf, D_MODEL);
  gemm_bt_mfma<<<dim3(8,393),256,0,stream>>>(u_bf, emb_bf, nullptr, out,
                                             1024, VOCAB, D_MODEL);
}